// Round 12
// baseline (384.717 us; speedup 1.0000x reference)
//
#include <hip/hip_runtime.h>

#define N_PIX 16384
#define CC 192
#define C3 576
#define KTOT 192
#define NCH 32
#define CHUNK 512

typedef __bf16 bf16_t;
typedef bf16_t bf16x4 __attribute__((ext_vector_type(4)));
typedef bf16_t bf16x8 __attribute__((ext_vector_type(8)));
typedef float f32x4 __attribute__((ext_vector_type(4)));

struct WPtrs { const float* p[4]; };
struct GArgs { const float* W[16]; long xoff[16]; int sel[16]; };

// ---------------- MFMA GEMM: Y[m][n] = sum_k W[m][k] * X[k][n], K=192 --------
// 64m x 128n tile (NI=2). W staged to LDS once (full K, 25.6KB, ONE barrier).
// X loaded per-thread directly from global (barrier-free K-loop, round-11).
// acc halved 64->32 AGPR: rounds 9-11 showed occupancy tracks VGPR+AGPR
// unified count (~140 -> 3 waves/SIMD); ~105 should give 4-5. Latency-bound
// kernel => waves/SIMD is THE lever. A/B frags share k-bijection
// phi(gi,e)=16*(e>>2)+4*gi+(e&3); C/D col=lane&15, row=4*(lane>>4)+reg [m89].
template <typename XT, typename YT>
__global__ __launch_bounds__(256) void gemm_k192(GArgs ga,
    const XT* __restrict__ X0, const XT* __restrict__ X1,
    YT* __restrict__ Y, long sY)
{
    __shared__ __align__(16) bf16_t Wl[64][200];   // 64m x 192k (+8 pad)
    const int bt = blockIdx.z;
    const float* __restrict__ W = ga.W[bt];
    const XT* __restrict__ Xb = (ga.sel[bt] ? X1 : X0) + ga.xoff[bt];
    YT* __restrict__ Yb = Y + (long)bt * sY;
    const int m0 = blockIdx.y * 64, n0 = blockIdx.x * 128;
    const int tid = threadIdx.x;
    const int w = tid >> 6;
    const int gi = (tid >> 4) & 3;
    const int li = tid & 15;

    // stage all of W: 4 threads/row, each 48 k = 6 bf16x8 segments
    {
        const int wr = tid >> 2, wkb = (tid & 3) * 48;
        #pragma unroll
        for (int j = 0; j < 6; ++j) {
            const float* wp0 = W + (long)(m0 + wr) * KTOT + wkb + 8 * j;
            float4 a = *(const float4*)(wp0);
            float4 b = *(const float4*)(wp0 + 4);
            bf16x8 v = { (bf16_t)a.x, (bf16_t)a.y, (bf16_t)a.z, (bf16_t)a.w,
                         (bf16_t)b.x, (bf16_t)b.y, (bf16_t)b.z, (bf16_t)b.w };
            *(bf16x8*)&Wl[wr][wkb + 8 * j] = v;
        }
    }
    __syncthreads();                    // the ONLY barrier

    f32x4 acc[4][2];
    #pragma unroll
    for (int i = 0; i < 4; ++i)
        #pragma unroll
        for (int j = 0; j < 2; ++j) acc[i][j] = 0.f;

    // per-thread column base: n(ni) = n0 + 32w + 16ni + li
    const XT* xcol = Xb + n0 + 32 * w + li;

    for (int t = 0; t < 6; ++t) {
        const int kb = 32 * t;
        bf16x8 bfr[2];
        #pragma unroll
        for (int ni = 0; ni < 2; ++ni) {
            // elem e -> k = kb + 16*(e>>2) + 4*gi + (e&3)
            const XT* xp = xcol + 16 * ni + (long)(kb + 4 * gi) * N_PIX;
            bf16x8 v;
            #pragma unroll
            for (int e2 = 0; e2 < 4; ++e2) {
                v[e2]     = (bf16_t)xp[(long)e2 * N_PIX];
                v[e2 + 4] = (bf16_t)xp[(long)(16 + e2) * N_PIX];
            }
            bfr[ni] = v;
        }
        bf16x8 af[4];
        #pragma unroll
        for (int mi = 0; mi < 4; ++mi) {
            bf16x4 lo = *(const bf16x4*)&Wl[16 * mi + li][kb + 4 * gi];
            bf16x4 hi = *(const bf16x4*)&Wl[16 * mi + li][kb + 16 + 4 * gi];
            af[mi] = __builtin_shufflevector(lo, hi, 0, 1, 2, 3, 4, 5, 6, 7);
        }
        #pragma unroll
        for (int mi = 0; mi < 4; ++mi)
            #pragma unroll
            for (int ni = 0; ni < 2; ++ni)
                acc[mi][ni] = __builtin_amdgcn_mfma_f32_16x16x32_bf16(
                    af[mi], bfr[ni], acc[mi][ni], 0, 0, 0);
    }
    #pragma unroll
    for (int mi = 0; mi < 4; ++mi)
        #pragma unroll
        for (int ni = 0; ni < 2; ++ni) {
            const int n = n0 + 32 * w + 16 * ni + li;
            #pragma unroll
            for (int r = 0; r < 4; ++r) {
                const int m = m0 + 16 * mi + 4 * gi + r;
                Yb[(long)m * N_PIX + n] = (YT)acc[mi][ni][r];
            }
        }
}

// ---------------- depthwise 3x3 + fused row L2-norm ----------------
// One block = one (channel, image) = one full norm row. For ch<384 (q,k),
// block-reduce sum(z^2) over the 128x128 output and write invn directly.
__global__ __launch_bounds__(256) void dwconv3b(const bf16_t* __restrict__ Yin,
    const float* __restrict__ wdw, bf16_t* __restrict__ Z,
    float* __restrict__ invn)
{
    const int ch = blockIdx.x, sb = blockIdx.y;
    const int tid = threadIdx.x;
    const int x0 = (tid & 15) << 3;          // 16 col-groups x 8
    const int y0 = (tid >> 4) << 3;          // 16 row-strips x 8
    const bf16_t* __restrict__ inp = Yin + (long)(sb * C3 + ch) * N_PIX;
    bf16_t* __restrict__ outp = Z + (long)(sb * C3 + ch) * N_PIX;
    const float* wch = wdw + ch * 9;
    const float w00 = wch[0], w01 = wch[1], w02 = wch[2];
    const float w10 = wch[3], w11 = wch[4], w12 = wch[5];
    const float w20 = wch[6], w21 = wch[7], w22 = wch[8];
    const bool hasL = (x0 > 0), hasR = (x0 < 120);
    float A[10], B[10], Cr[10];   // [0]=x0-1, [1..8]=x0..x0+7, [9]=x0+8
    auto loadrow = [&](int yy, float* r) {
        if (yy < 0 || yy > 127) {
            #pragma unroll
            for (int i = 0; i < 10; ++i) r[i] = 0.f;
            return;
        }
        const bf16_t* p = inp + (yy << 7);
        bf16x8 v = *(const bf16x8*)(p + x0);
        #pragma unroll
        for (int j = 0; j < 8; ++j) r[1 + j] = (float)v[j];
        r[0] = hasL ? (float)p[x0 - 1] : 0.f;
        r[9] = hasR ? (float)p[x0 + 8] : 0.f;
    };
    loadrow(y0 - 1, A);
    loadrow(y0,     B);
    float ss = 0.f;
    #pragma unroll
    for (int r = 0; r < 8; ++r) {
        loadrow(y0 + r + 1, Cr);
        bf16x8 ov;
        #pragma unroll
        for (int i = 0; i < 8; ++i) {
            float s;
            s = fmaf(w00, A[i],  fmaf(w01, A[i + 1],  w02 * A[i + 2]));
            s = fmaf(w10, B[i],  fmaf(w11, B[i + 1],  fmaf(w12, B[i + 2], s)));
            s = fmaf(w20, Cr[i], fmaf(w21, Cr[i + 1], fmaf(w22, Cr[i + 2], s)));
            ov[i] = (bf16_t)s;
            const float vb = (float)ov[i];   // norm of the bf16-rounded value
            ss = fmaf(vb, vb, ss);
        }
        *(bf16x8*)(outp + ((y0 + r) << 7) + x0) = ov;
        #pragma unroll
        for (int i = 0; i < 10; ++i) { A[i] = B[i]; B[i] = Cr[i]; }
    }
    if (ch < 384) {
        #pragma unroll
        for (int off = 32; off > 0; off >>= 1) ss += __shfl_down(ss, off);
        __shared__ float red[4];
        if ((tid & 63) == 0) red[tid >> 6] = ss;
        __syncthreads();
        if (tid == 0) {
            const float t = red[0] + red[1] + red[2] + red[3];
            const int row = (sb >> 2) * 1536 + (sb & 3) * 384 + ch;
            invn[row] = 1.f / fmaxf(sqrtf(t), 1e-12f);
        }
    }
}

// ---------------- MFMA score partials: all 4 combos share one LDS stage ------
// block = (chunk, b*4+h); wave m = combo (ee, dd, ed, de).
__global__ __launch_bounds__(256) void scores_mfma(const bf16_t* __restrict__ Z,
                                                   float* __restrict__ part)
{
    const int c = blockIdx.x;
    const int bh = blockIdx.y;
    const int b = bh >> 2, h = bh & 3;
    __shared__ __align__(16) bf16_t T[4][48][72];   // qe, qd, ke, kd
    const int tid = threadIdx.x;
    const int m = tid >> 6;
    const int gi = (tid >> 4) & 3, li = tid & 15;
    const int qs = (m == 1 || m == 3) ? 1 : 0;
    const int ks = (m == 1 || m == 2) ? 1 : 0;
    f32x4 acc[3][3];
    #pragma unroll
    for (int i = 0; i < 3; ++i)
        #pragma unroll
        for (int j = 0; j < 3; ++j) acc[i][j] = 0.f;

    const int nbase = c * CHUNK;
    for (int k0 = 0; k0 < CHUNK; k0 += 64) {
        __syncthreads();
        for (int l = tid; l < 1536; l += 256) {
            const int t = l / 384;
            const int rem = l - t * 384;
            const int r = rem >> 3, s = rem & 7;
            const int sidx = (t < 2) ? t : (t - 2);
            const int qk = (t < 2) ? 0 : 1;
            const bf16_t* gp = Z + ((long)((sidx * 4 + b) * C3 + qk * 192 + h * 48 + r)) * N_PIX
                                 + nbase + k0 + s * 8;
            *(bf16x8*)&T[t][r][s * 8] = *(const bf16x8*)gp;
        }
        __syncthreads();
        #pragma unroll
        for (int k2 = 0; k2 < 64; k2 += 32) {
            bf16x8 af[3], bfr[3];
            #pragma unroll
            for (int i = 0; i < 3; ++i) {
                bf16x4 lo = *(const bf16x4*)&T[qs][16 * i + li][k2 + 4 * gi];
                bf16x4 hi = *(const bf16x4*)&T[qs][16 * i + li][k2 + 16 + 4 * gi];
                af[i] = __builtin_shufflevector(lo, hi, 0, 1, 2, 3, 4, 5, 6, 7);
            }
            #pragma unroll
            for (int j = 0; j < 3; ++j) {
                bf16x4 lo = *(const bf16x4*)&T[2 + ks][16 * j + li][k2 + 4 * gi];
                bf16x4 hi = *(const bf16x4*)&T[2 + ks][16 * j + li][k2 + 16 + 4 * gi];
                bfr[j] = __builtin_shufflevector(lo, hi, 0, 1, 2, 3, 4, 5, 6, 7);
            }
            #pragma unroll
            for (int i = 0; i < 3; ++i)
                #pragma unroll
                for (int j = 0; j < 3; ++j)
                    acc[i][j] = __builtin_amdgcn_mfma_f32_16x16x32_bf16(
                        af[i], bfr[j], acc[i][j], 0, 0, 0);
        }
    }
    const long base = ((long)(m * 16 + bh) * NCH + c) * 2304;
    #pragma unroll
    for (int i = 0; i < 3; ++i)
        #pragma unroll
        for (int j = 0; j < 3; ++j) {
            const int e = 16 * j + li;
            #pragma unroll
            for (int r = 0; r < 4; ++r) {
                const int d = 16 * i + 4 * gi + r;
                part[base + d * 48 + e] = acc[i][j][r];
            }
        }
}

// ---------------- reduce partials, scale by norms+temperature, softmax -------
__global__ __launch_bounds__(256) void reduce_softmax(const float* __restrict__ part,
    const float* __restrict__ invn, const float* __restrict__ temp,
    float* __restrict__ attn)
{
    const int mbh = blockIdx.x;                 // 64
    const int m = mbh >> 4, b = (mbh >> 2) & 3, h = mbh & 3;
    const int qs = (m == 1 || m == 3) ? 1 : 0;
    const int ks = (m == 1 || m == 2) ? 1 : 0;
    __shared__ float sm[48][48];
    const int tid = threadIdx.x;
    const long pbase = (long)mbh * NCH * 2304;
    const float T = temp[h];
    for (int idx = tid; idx < 2304; idx += 256) {
        float v = 0.f;
        #pragma unroll 8
        for (int c = 0; c < NCH; ++c) v += part[pbase + c * 2304 + idx];
        const int d = idx / 48, e = idx % 48;
        const float iq = invn[(qs * 4 + b) * 384 + h * 48 + d];
        const float ik = invn[(ks * 4 + b) * 384 + 192 + h * 48 + e];
        sm[d][e] = v * iq * ik * T;
    }
    __syncthreads();
    if (tid < 48) {
        float mx = -1e30f;
        #pragma unroll
        for (int e = 0; e < 48; ++e) mx = fmaxf(mx, sm[tid][e]);
        float sum = 0.f;
        #pragma unroll
        for (int e = 0; e < 48; ++e) {
            const float v = __expf(sm[tid][e] - mx);
            sm[tid][e] = v;
            sum += v;
        }
        const float inv = 1.f / sum;
        const long abase = (long)mbh * 2304 + (long)tid * 48;
        #pragma unroll
        for (int e = 0; e < 48; ++e) attn[abase + e] = sm[tid][e] * inv;
    }
}

// ---------------- fold attn into projection: M[m][b][o][h*48+e] --------------
// m==3 (inter_de): einsum '...de,bhen->bhdn' SUMS the ellipsis dims.
__global__ __launch_bounds__(256) void make_M(const float* __restrict__ attn,
                                              WPtrs wp, float* __restrict__ M)
{
    const int h = blockIdx.x & 3;
    const int b = (blockIdx.x >> 2) & 3;
    const int m = blockIdx.x >> 4;              // grid 64
    __shared__ float A[48][48];
    const int tid = threadIdx.x;
    if (m == 3) {
        for (int l = tid; l < 2304; l += 256) {
            float s = 0.f;
            #pragma unroll
            for (int bb = 0; bb < 16; ++bb)
                s += attn[(long)(48 + bb) * 2304 + l];
            A[l / 48][l % 48] = s;
        }
    } else {
        const long ab = (long)(m * 16 + b * 4 + h) * 2304;
        for (int l = tid; l < 2304; l += 256)
            A[l / 48][l % 48] = attn[ab + l];
    }
    __syncthreads();
    const float* W = wp.p[m];
    float* Mo = M + (long)(m * 4 + b) * 192 * 192;
    for (int o = tid >> 4; o < 192; o += 16) {
        const float* wrow = W + (long)o * 192 + h * 48;
        for (int e2 = tid & 15; e2 < 48; e2 += 16) {
            float s = 0.f;
            #pragma unroll
            for (int d = 0; d < 48; ++d) s = fmaf(wrow[d], A[d][e2], s);
            Mo[(long)o * 192 + h * 48 + e2] = s;
        }
    }
}

extern "C" void kernel_launch(void* const* d_in, const int* in_sizes, int n_in,
                              void* d_out, int out_size, void* d_ws, size_t ws_size,
                              hipStream_t stream)
{
    const float* e     = (const float*)d_in[0];
    const float* d     = (const float*)d_in[1];
    const float* temp  = (const float*)d_in[2];
    const float* w_qkv = (const float*)d_in[3];
    const float* w_dw  = (const float*)d_in[4];
    const float* w_p1  = (const float*)d_in[5];
    const float* w_p2  = (const float*)d_in[6];
    const float* w_p3  = (const float*)d_in[7];
    const float* w_p4  = (const float*)d_in[8];
    float* out = (float*)d_out;
    float* ws  = (float*)d_ws;

    // workspace layout (float units)
    bf16_t* zraw = (bf16_t*)ws;                // 75,497,472 bf16 (qkv raw)
    bf16_t* zb   = (bf16_t*)(ws + 37748736L);  // 75,497,472 bf16
    float* attn  = ws + 75497472L;             // 147,456
    float* invn  = ws + 75644928L;             // 3,072
    // part & M reuse the zraw region once it's dead (after dwconv3b)
    float* part  = ws;                         // 4,718,592 f32
    float* Mmat  = ws + 8388608L;              // 589,824 f32

    const long sXin = (long)CC * N_PIX;
    const long sQKV = (long)C3 * N_PIX;

    // 1) pointwise qkv GEMM, bf16 output — ONE launch for e (bt 0..3, X0) and
    //    d (bt 4..7, X1): d-GEMM ramp overlaps e-GEMM drain.
    GArgs gq{};
    for (int bt = 0; bt < 8; ++bt) {
        gq.W[bt] = w_qkv;
        gq.xoff[bt] = (long)(bt & 3) * sXin;
        gq.sel[bt] = bt >> 2;
    }
    gemm_k192<float, bf16_t><<<dim3(128, 9, 8), 256, 0, stream>>>(gq, e, d, zraw, sQKV);
    // 2) depthwise 3x3 (bf16 -> bf16) + fused q/k row norms
    dwconv3b<<<dim3(C3, 8), 256, 0, stream>>>(zraw, w_dw, zb, invn);
    // 3) MFMA score partials, 4 combos fused (part reuses dead zraw region)
    scores_mfma<<<dim3(NCH, 16), 256, 0, stream>>>(zb, part);
    // 4) reduce + scale + softmax
    reduce_softmax<<<dim3(64), 256, 0, stream>>>(part, invn, temp, attn);
    // 5) fold attn into projection matrices
    WPtrs wpj; wpj.p[0] = w_p1; wpj.p[1] = w_p2; wpj.p[2] = w_p3; wpj.p[3] = w_p4;
    make_M<<<dim3(64), 256, 0, stream>>>(attn, wpj, Mmat);
    // 6) fused (proj ∘ attn) @ V directly into d_out (V is bf16)
    GArgs gm{};
    for (int bt = 0; bt < 16; ++bt) {
        const int m = bt >> 2, b = bt & 3;
        const int ks = (m == 1 || m == 2) ? 1 : 0;
        gm.W[bt] = Mmat + (long)bt * 192 * 192;
        gm.xoff[bt] = ((long)((ks * 4 + b) * C3 + 384)) * N_PIX;
        gm.sel[bt] = 0;
    }
    gemm_k192<bf16_t, float><<<dim3(128, 3, 16), 256, 0, stream>>>(gm, zb, zb, out, sXin);
}

// Round 13
// 373.186 us; speedup vs baseline: 1.0309x; 1.0309x over previous
//
#include <hip/hip_runtime.h>

#define N_PIX 16384
#define CC 192
#define C3 576
#define KTOT 192
#define NCH 32
#define CHUNK 512

typedef __bf16 bf16_t;
typedef bf16_t bf16x4 __attribute__((ext_vector_type(4)));
typedef bf16_t bf16x8 __attribute__((ext_vector_type(8)));
typedef float f32x4 __attribute__((ext_vector_type(4)));

struct WPtrs { const float* p[4]; };
struct GArgs { const float* W[16]; long xoff[16]; int sel[16]; };

// ---------------- MFMA GEMM: Y[m][n] = sum_k W[m][k] * X[k][n], K=192 --------
// 64m x 128n tile. W staged to LDS once (full K). X staged per 32-k tile with
// VECTORIZED n-contiguous 16B loads (f32: 4 dwordx4/thread/tile; bf16: 2) into
// a k-major LDS tile. Rounds 7-12 were invariant at 126-137us because every
// variant used 192 k-strided SCALAR loads/thread (4 segments/wave-instr) —
// VMEM segment throughput was the bottleneck, untouched by LDS/barrier/
// occupancy changes. A/B frags share k-bijection phi(gi,e)=16*(e>>2)+4*gi+
// (e&3); C/D map col=lane&15, row=4*(lane>>4)+reg [m89-verified].
template <typename XT, typename YT>
__global__ __launch_bounds__(256) void gemm_k192(GArgs ga,
    const XT* __restrict__ X0, const XT* __restrict__ X1,
    YT* __restrict__ Y, long sY)
{
    __shared__ __align__(16) bf16_t Wl[64][200];   // 64m x 192k (+8 pad) 25.6KB
    __shared__ __align__(16) bf16_t Xl[32][140];   // 32k x 128n (+12 pad) 8.75KB
    const int bt = blockIdx.z;
    const float* __restrict__ W = ga.W[bt];
    const XT* __restrict__ Xb = (ga.sel[bt] ? X1 : X0) + ga.xoff[bt];
    YT* __restrict__ Yb = Y + (long)bt * sY;
    const int m0 = blockIdx.y * 64, n0 = blockIdx.x * 128;
    const int tid = threadIdx.x;
    const int w = tid >> 6;
    const int gi = (tid >> 4) & 3;
    const int li = tid & 15;

    constexpr int EPL = 16 / sizeof(XT);        // elems per 16B load (f32:4, bf16:8)
    constexpr int CGRP = 128 / EPL;             // col groups per row (32 / 16)
    constexpr int RPR = 256 / CGRP;             // rows per round (8 / 16)
    constexpr int NRND = 32 / RPR;              // rounds (4 / 2)
    const int xc = tid % CGRP;                  // col group
    const int xg = tid / CGRP;                  // row within round

    float4 xf[4];                                // f32 staging regs
    bf16x8 xh[2];                                // bf16 staging regs

    auto loadX = [&](int t) {
        const int kb = 32 * t;
        if constexpr (sizeof(XT) == 4) {
            #pragma unroll
            for (int i = 0; i < NRND; ++i)
                xf[i] = *(const float4*)(Xb + (long)(kb + RPR * i + xg) * N_PIX
                                         + n0 + EPL * xc);
        } else {
            #pragma unroll
            for (int i = 0; i < NRND; ++i)
                xh[i] = *(const bf16x8*)(Xb + (long)(kb + RPR * i + xg) * N_PIX
                                         + n0 + EPL * xc);
        }
    };
    auto writeX = [&]() {
        if constexpr (sizeof(XT) == 4) {
            #pragma unroll
            for (int i = 0; i < NRND; ++i) {
                bf16x4 v = { (bf16_t)xf[i].x, (bf16_t)xf[i].y,
                             (bf16_t)xf[i].z, (bf16_t)xf[i].w };
                *(bf16x4*)&Xl[RPR * i + xg][EPL * xc] = v;
            }
        } else {
            #pragma unroll
            for (int i = 0; i < NRND; ++i) {
                bf16x4 lo = { xh[i][0], xh[i][1], xh[i][2], xh[i][3] };
                bf16x4 hi = { xh[i][4], xh[i][5], xh[i][6], xh[i][7] };
                *(bf16x4*)&Xl[RPR * i + xg][EPL * xc]     = lo;  // row stride 280B:
                *(bf16x4*)&Xl[RPR * i + xg][EPL * xc + 4] = hi;  // 8B- not 16B-aligned
            }
        }
    };

    loadX(0);
    // stage all of W: 4 threads/row, each 48 k = 6 bf16x8 segments
    {
        const int wr = tid >> 2, wkb = (tid & 3) * 48;
        #pragma unroll
        for (int j = 0; j < 6; ++j) {
            const float* wp0 = W + (long)(m0 + wr) * KTOT + wkb + 8 * j;
            float4 a = *(const float4*)(wp0);
            float4 b = *(const float4*)(wp0 + 4);
            bf16x8 v = { (bf16_t)a.x, (bf16_t)a.y, (bf16_t)a.z, (bf16_t)a.w,
                         (bf16_t)b.x, (bf16_t)b.y, (bf16_t)b.z, (bf16_t)b.w };
            *(bf16x8*)&Wl[wr][wkb + 8 * j] = v;
        }
    }

    f32x4 acc[4][2];
    #pragma unroll
    for (int i = 0; i < 4; ++i)
        #pragma unroll
        for (int j = 0; j < 2; ++j) acc[i][j] = 0.f;

    const int nn = 32 * w + li;                 // frag n base (+16*ni)

    for (int t = 0; t < 6; ++t) {
        const int kb = 32 * t;
        writeX();                                // regs(t) -> LDS
        if (t < 5) loadX(t + 1);                 // issue next loads under MFMAs
        __syncthreads();                         // Xl (and Wl at t=0) ready
        bf16x8 af[4], bfr[2];
        #pragma unroll
        for (int mi = 0; mi < 4; ++mi) {
            bf16x4 lo = *(const bf16x4*)&Wl[16 * mi + li][kb + 4 * gi];
            bf16x4 hi = *(const bf16x4*)&Wl[16 * mi + li][kb + 16 + 4 * gi];
            af[mi] = __builtin_shufflevector(lo, hi, 0, 1, 2, 3, 4, 5, 6, 7);
        }
        #pragma unroll
        for (int ni = 0; ni < 2; ++ni) {
            bf16x8 v;
            #pragma unroll
            for (int eh = 0; eh < 2; ++eh)
                #pragma unroll
                for (int e2 = 0; e2 < 4; ++e2)
                    v[eh * 4 + e2] = Xl[16 * eh + 4 * gi + e2][nn + 16 * ni];
            bfr[ni] = v;
        }
        #pragma unroll
        for (int mi = 0; mi < 4; ++mi)
            #pragma unroll
            for (int ni = 0; ni < 2; ++ni)
                acc[mi][ni] = __builtin_amdgcn_mfma_f32_16x16x32_bf16(
                    af[mi], bfr[ni], acc[mi][ni], 0, 0, 0);
        __syncthreads();                         // before next iter's writes
    }
    #pragma unroll
    for (int mi = 0; mi < 4; ++mi)
        #pragma unroll
        for (int ni = 0; ni < 2; ++ni) {
            const int n = n0 + 32 * w + 16 * ni + li;
            #pragma unroll
            for (int r = 0; r < 4; ++r) {
                const int m = m0 + 16 * mi + 4 * gi + r;
                Yb[(long)m * N_PIX + n] = (YT)acc[mi][ni][r];
            }
        }
}

// ---------------- depthwise 3x3 + fused row L2-norm ----------------
// One block = one (channel, image) = one full norm row. For ch<384 (q,k),
// block-reduce sum(z^2) over the 128x128 output and write invn directly.
__global__ __launch_bounds__(256) void dwconv3b(const bf16_t* __restrict__ Yin,
    const float* __restrict__ wdw, bf16_t* __restrict__ Z,
    float* __restrict__ invn)
{
    const int ch = blockIdx.x, sb = blockIdx.y;
    const int tid = threadIdx.x;
    const int x0 = (tid & 15) << 3;          // 16 col-groups x 8
    const int y0 = (tid >> 4) << 3;          // 16 row-strips x 8
    const bf16_t* __restrict__ inp = Yin + (long)(sb * C3 + ch) * N_PIX;
    bf16_t* __restrict__ outp = Z + (long)(sb * C3 + ch) * N_PIX;
    const float* wch = wdw + ch * 9;
    const float w00 = wch[0], w01 = wch[1], w02 = wch[2];
    const float w10 = wch[3], w11 = wch[4], w12 = wch[5];
    const float w20 = wch[6], w21 = wch[7], w22 = wch[8];
    const bool hasL = (x0 > 0), hasR = (x0 < 120);
    float A[10], B[10], Cr[10];   // [0]=x0-1, [1..8]=x0..x0+7, [9]=x0+8
    auto loadrow = [&](int yy, float* r) {
        if (yy < 0 || yy > 127) {
            #pragma unroll
            for (int i = 0; i < 10; ++i) r[i] = 0.f;
            return;
        }
        const bf16_t* p = inp + (yy << 7);
        bf16x8 v = *(const bf16x8*)(p + x0);
        #pragma unroll
        for (int j = 0; j < 8; ++j) r[1 + j] = (float)v[j];
        r[0] = hasL ? (float)p[x0 - 1] : 0.f;
        r[9] = hasR ? (float)p[x0 + 8] : 0.f;
    };
    loadrow(y0 - 1, A);
    loadrow(y0,     B);
    float ss = 0.f;
    #pragma unroll
    for (int r = 0; r < 8; ++r) {
        loadrow(y0 + r + 1, Cr);
        bf16x8 ov;
        #pragma unroll
        for (int i = 0; i < 8; ++i) {
            float s;
            s = fmaf(w00, A[i],  fmaf(w01, A[i + 1],  w02 * A[i + 2]));
            s = fmaf(w10, B[i],  fmaf(w11, B[i + 1],  fmaf(w12, B[i + 2], s)));
            s = fmaf(w20, Cr[i], fmaf(w21, Cr[i + 1], fmaf(w22, Cr[i + 2], s)));
            ov[i] = (bf16_t)s;
            const float vb = (float)ov[i];   // norm of the bf16-rounded value
            ss = fmaf(vb, vb, ss);
        }
        *(bf16x8*)(outp + ((y0 + r) << 7) + x0) = ov;
        #pragma unroll
        for (int i = 0; i < 10; ++i) { A[i] = B[i]; B[i] = Cr[i]; }
    }
    if (ch < 384) {
        #pragma unroll
        for (int off = 32; off > 0; off >>= 1) ss += __shfl_down(ss, off);
        __shared__ float red[4];
        if ((tid & 63) == 0) red[tid >> 6] = ss;
        __syncthreads();
        if (tid == 0) {
            const float t = red[0] + red[1] + red[2] + red[3];
            const int row = (sb >> 2) * 1536 + (sb & 3) * 384 + ch;
            invn[row] = 1.f / fmaxf(sqrtf(t), 1e-12f);
        }
    }
}

// ---------------- MFMA score partials: all 4 combos share one LDS stage ------
// block = (chunk, b*4+h); wave m = combo (ee, dd, ed, de).
__global__ __launch_bounds__(256) void scores_mfma(const bf16_t* __restrict__ Z,
                                                   float* __restrict__ part)
{
    const int c = blockIdx.x;
    const int bh = blockIdx.y;
    const int b = bh >> 2, h = bh & 3;
    __shared__ __align__(16) bf16_t T[4][48][72];   // qe, qd, ke, kd
    const int tid = threadIdx.x;
    const int m = tid >> 6;
    const int gi = (tid >> 4) & 3, li = tid & 15;
    const int qs = (m == 1 || m == 3) ? 1 : 0;
    const int ks = (m == 1 || m == 2) ? 1 : 0;
    f32x4 acc[3][3];
    #pragma unroll
    for (int i = 0; i < 3; ++i)
        #pragma unroll
        for (int j = 0; j < 3; ++j) acc[i][j] = 0.f;

    const int nbase = c * CHUNK;
    for (int k0 = 0; k0 < CHUNK; k0 += 64) {
        __syncthreads();
        for (int l = tid; l < 1536; l += 256) {
            const int t = l / 384;
            const int rem = l - t * 384;
            const int r = rem >> 3, s = rem & 7;
            const int sidx = (t < 2) ? t : (t - 2);
            const int qk = (t < 2) ? 0 : 1;
            const bf16_t* gp = Z + ((long)((sidx * 4 + b) * C3 + qk * 192 + h * 48 + r)) * N_PIX
                                 + nbase + k0 + s * 8;
            *(bf16x8*)&T[t][r][s * 8] = *(const bf16x8*)gp;
        }
        __syncthreads();
        #pragma unroll
        for (int k2 = 0; k2 < 64; k2 += 32) {
            bf16x8 af[3], bfr[3];
            #pragma unroll
            for (int i = 0; i < 3; ++i) {
                bf16x4 lo = *(const bf16x4*)&T[qs][16 * i + li][k2 + 4 * gi];
                bf16x4 hi = *(const bf16x4*)&T[qs][16 * i + li][k2 + 16 + 4 * gi];
                af[i] = __builtin_shufflevector(lo, hi, 0, 1, 2, 3, 4, 5, 6, 7);
            }
            #pragma unroll
            for (int j = 0; j < 3; ++j) {
                bf16x4 lo = *(const bf16x4*)&T[2 + ks][16 * j + li][k2 + 4 * gi];
                bf16x4 hi = *(const bf16x4*)&T[2 + ks][16 * j + li][k2 + 16 + 4 * gi];
                bfr[j] = __builtin_shufflevector(lo, hi, 0, 1, 2, 3, 4, 5, 6, 7);
            }
            #pragma unroll
            for (int i = 0; i < 3; ++i)
                #pragma unroll
                for (int j = 0; j < 3; ++j)
                    acc[i][j] = __builtin_amdgcn_mfma_f32_16x16x32_bf16(
                        af[i], bfr[j], acc[i][j], 0, 0, 0);
        }
    }
    const long base = ((long)(m * 16 + bh) * NCH + c) * 2304;
    #pragma unroll
    for (int i = 0; i < 3; ++i)
        #pragma unroll
        for (int j = 0; j < 3; ++j) {
            const int e = 16 * j + li;
            #pragma unroll
            for (int r = 0; r < 4; ++r) {
                const int d = 16 * i + 4 * gi + r;
                part[base + d * 48 + e] = acc[i][j][r];
            }
        }
}

// ---------------- reduce partials, scale by norms+temperature, softmax -------
__global__ __launch_bounds__(256) void reduce_softmax(const float* __restrict__ part,
    const float* __restrict__ invn, const float* __restrict__ temp,
    float* __restrict__ attn)
{
    const int mbh = blockIdx.x;                 // 64
    const int m = mbh >> 4, b = (mbh >> 2) & 3, h = mbh & 3;
    const int qs = (m == 1 || m == 3) ? 1 : 0;
    const int ks = (m == 1 || m == 2) ? 1 : 0;
    __shared__ float sm[48][48];
    const int tid = threadIdx.x;
    const long pbase = (long)mbh * NCH * 2304;
    const float T = temp[h];
    for (int idx = tid; idx < 2304; idx += 256) {
        float v = 0.f;
        #pragma unroll 8
        for (int c = 0; c < NCH; ++c) v += part[pbase + c * 2304 + idx];
        const int d = idx / 48, e = idx % 48;
        const float iq = invn[(qs * 4 + b) * 384 + h * 48 + d];
        const float ik = invn[(ks * 4 + b) * 384 + 192 + h * 48 + e];
        sm[d][e] = v * iq * ik * T;
    }
    __syncthreads();
    if (tid < 48) {
        float mx = -1e30f;
        #pragma unroll
        for (int e = 0; e < 48; ++e) mx = fmaxf(mx, sm[tid][e]);
        float sum = 0.f;
        #pragma unroll
        for (int e = 0; e < 48; ++e) {
            const float v = __expf(sm[tid][e] - mx);
            sm[tid][e] = v;
            sum += v;
        }
        const float inv = 1.f / sum;
        const long abase = (long)mbh * 2304 + (long)tid * 48;
        #pragma unroll
        for (int e = 0; e < 48; ++e) attn[abase + e] = sm[tid][e] * inv;
    }
}

// ---------------- fold attn into projection: M[m][b][o][h*48+e] --------------
// m==3 (inter_de): einsum '...de,bhen->bhdn' SUMS the ellipsis dims.
__global__ __launch_bounds__(256) void make_M(const float* __restrict__ attn,
                                              WPtrs wp, float* __restrict__ M)
{
    const int h = blockIdx.x & 3;
    const int b = (blockIdx.x >> 2) & 3;
    const int m = blockIdx.x >> 4;              // grid 64
    __shared__ float A[48][48];
    const int tid = threadIdx.x;
    if (m == 3) {
        for (int l = tid; l < 2304; l += 256) {
            float s = 0.f;
            #pragma unroll
            for (int bb = 0; bb < 16; ++bb)
                s += attn[(long)(48 + bb) * 2304 + l];
            A[l / 48][l % 48] = s;
        }
    } else {
        const long ab = (long)(m * 16 + b * 4 + h) * 2304;
        for (int l = tid; l < 2304; l += 256)
            A[l / 48][l % 48] = attn[ab + l];
    }
    __syncthreads();
    const float* W = wp.p[m];
    float* Mo = M + (long)(m * 4 + b) * 192 * 192;
    for (int o = tid >> 4; o < 192; o += 16) {
        const float* wrow = W + (long)o * 192 + h * 48;
        for (int e2 = tid & 15; e2 < 48; e2 += 16) {
            float s = 0.f;
            #pragma unroll
            for (int d = 0; d < 48; ++d) s = fmaf(wrow[d], A[d][e2], s);
            Mo[(long)o * 192 + h * 48 + e2] = s;
        }
    }
}

extern "C" void kernel_launch(void* const* d_in, const int* in_sizes, int n_in,
                              void* d_out, int out_size, void* d_ws, size_t ws_size,
                              hipStream_t stream)
{
    const float* e     = (const float*)d_in[0];
    const float* d     = (const float*)d_in[1];
    const float* temp  = (const float*)d_in[2];
    const float* w_qkv = (const float*)d_in[3];
    const float* w_dw  = (const float*)d_in[4];
    const float* w_p1  = (const float*)d_in[5];
    const float* w_p2  = (const float*)d_in[6];
    const float* w_p3  = (const float*)d_in[7];
    const float* w_p4  = (const float*)d_in[8];
    float* out = (float*)d_out;
    float* ws  = (float*)d_ws;

    // workspace layout (float units)
    bf16_t* zraw = (bf16_t*)ws;                // 75,497,472 bf16 (qkv raw)
    bf16_t* zb   = (bf16_t*)(ws + 37748736L);  // 75,497,472 bf16
    float* attn  = ws + 75497472L;             // 147,456
    float* invn  = ws + 75644928L;             // 3,072
    // part & M reuse the zraw region once it's dead (after dwconv3b)
    float* part  = ws;                         // 4,718,592 f32
    float* Mmat  = ws + 8388608L;              // 589,824 f32

    const long sXin = (long)CC * N_PIX;
    const long sQKV = (long)C3 * N_PIX;

    // 1) pointwise qkv GEMM, bf16 output — ONE launch for e (bt 0..3, X0) and
    //    d (bt 4..7, X1): d-GEMM ramp overlaps e-GEMM drain.
    GArgs gq{};
    for (int bt = 0; bt < 8; ++bt) {
        gq.W[bt] = w_qkv;
        gq.xoff[bt] = (long)(bt & 3) * sXin;
        gq.sel[bt] = bt >> 2;
    }
    gemm_k192<float, bf16_t><<<dim3(128, 9, 8), 256, 0, stream>>>(gq, e, d, zraw, sQKV);
    // 2) depthwise 3x3 (bf16 -> bf16) + fused q/k row norms
    dwconv3b<<<dim3(C3, 8), 256, 0, stream>>>(zraw, w_dw, zb, invn);
    // 3) MFMA score partials, 4 combos fused (part reuses dead zraw region)
    scores_mfma<<<dim3(NCH, 16), 256, 0, stream>>>(zb, part);
    // 4) reduce + scale + softmax
    reduce_softmax<<<dim3(64), 256, 0, stream>>>(part, invn, temp, attn);
    // 5) fold attn into projection matrices
    WPtrs wpj; wpj.p[0] = w_p1; wpj.p[1] = w_p2; wpj.p[2] = w_p3; wpj.p[3] = w_p4;
    make_M<<<dim3(64), 256, 0, stream>>>(attn, wpj, Mmat);
    // 6) fused (proj ∘ attn) @ V directly into d_out (V is bf16)
    GArgs gm{};
    for (int bt = 0; bt < 16; ++bt) {
        const int m = bt >> 2, b = bt & 3;
        const int ks = (m == 1 || m == 2) ? 1 : 0;
        gm.W[bt] = Mmat + (long)bt * 192 * 192;
        gm.xoff[bt] = ((long)((ks * 4 + b) * C3 + 384)) * N_PIX;
        gm.sel[bt] = 0;
    }
    gemm_k192<bf16_t, float><<<dim3(128, 3, 16), 256, 0, stream>>>(gm, zb, zb, out, sXin);
}

// Round 14
// 368.373 us; speedup vs baseline: 1.0444x; 1.0131x over previous
//
#include <hip/hip_runtime.h>

#define N_PIX 16384
#define CC 192
#define C3 576
#define KTOT 192
#define NCH 32
#define CHUNK 512

typedef __bf16 bf16_t;
typedef bf16_t bf16x4 __attribute__((ext_vector_type(4)));
typedef bf16_t bf16x8 __attribute__((ext_vector_type(8)));
typedef float f32x4 __attribute__((ext_vector_type(4)));

struct WPtrs { const float* p[4]; };
struct GArgs { const float* W[16]; long xoff[16]; int sel[16]; };

// ---------------- MFMA GEMM: Y[m][n] = sum_k W[m][k] * X[k][n], K=192 --------
// 64m x 128n tile. W staged to LDS once (full K). X: each thread owns a 4kx4n
// micro-block — 4 n-contiguous 16B/8B global loads, 4x4 REGISTER transpose,
// 4 ds_write_b64 into n-major Xl, frags read back as ds_read_b64.
// Rounds 7-13 were invariant at 126-137us because every variant had ~40+
// SCALAR memory instrs/thread/iter (global k-strided OR ds_read_u16 — the
// transpose always landed on a scalar path saturating one unit). This makes
// both sides vector: LDS ops 48->16 per iter, global already 16B.
// A/B frags share k-bijection phi(gi,e)=16*(e>>2)+4*gi+(e&3); C/D map
// col=lane&15, row=4*(lane>>4)+reg [m89-verified].
template <typename XT, typename YT>
__global__ __launch_bounds__(256) void gemm_k192(GArgs ga,
    const XT* __restrict__ X0, const XT* __restrict__ X1,
    YT* __restrict__ Y, long sY)
{
    __shared__ __align__(16) bf16_t Wl[64][200];   // 64m x 192k (+8 pad) 25.6KB
    __shared__ __align__(16) bf16_t Xl[128][36];   // 128n x 32k (+4 pad)  9KB
    const int bt = blockIdx.z;
    const float* __restrict__ W = ga.W[bt];
    const XT* __restrict__ Xb = (ga.sel[bt] ? X1 : X0) + ga.xoff[bt];
    YT* __restrict__ Yb = Y + (long)bt * sY;
    const int m0 = blockIdx.y * 64, n0 = blockIdx.x * 128;
    const int tid = threadIdx.x;
    const int w = tid >> 6;
    const int gi = (tid >> 4) & 3;
    const int li = tid & 15;
    const int kb4 = tid >> 5;       // 0..7  : owns k rows 4*kb4..+3
    const int nb4 = tid & 31;       // 0..31 : owns n cols 4*nb4..+3

    f32x4 xf[4];                    // f32 staging (4 rows x 4 n)
    bf16x4 xh[4];                   // bf16 staging

    auto loadX = [&](int t) {
        const XT* p = Xb + (long)(32 * t + 4 * kb4) * N_PIX + n0 + 4 * nb4;
        #pragma unroll
        for (int j = 0; j < 4; ++j) {
            if constexpr (sizeof(XT) == 4)
                xf[j] = *(const f32x4*)(p + (long)j * N_PIX);
            else
                xh[j] = *(const bf16x4*)(p + (long)j * N_PIX);
        }
    };
    auto writeX = [&]() {           // 4x4 register transpose -> n-major LDS
        #pragma unroll
        for (int i = 0; i < 4; ++i) {
            bf16x4 v;
            if constexpr (sizeof(XT) == 4)
                v = bf16x4{ (bf16_t)xf[0][i], (bf16_t)xf[1][i],
                            (bf16_t)xf[2][i], (bf16_t)xf[3][i] };
            else
                v = bf16x4{ xh[0][i], xh[1][i], xh[2][i], xh[3][i] };
            *(bf16x4*)&Xl[4 * nb4 + i][4 * kb4] = v;
        }
    };

    loadX(0);
    // stage all of W: 4 threads/row, each 48 k = 6 bf16x8 segments
    {
        const int wr = tid >> 2, wkb = (tid & 3) * 48;
        #pragma unroll
        for (int j = 0; j < 6; ++j) {
            const float* wp0 = W + (long)(m0 + wr) * KTOT + wkb + 8 * j;
            float4 a = *(const float4*)(wp0);
            float4 b = *(const float4*)(wp0 + 4);
            bf16x8 v = { (bf16_t)a.x, (bf16_t)a.y, (bf16_t)a.z, (bf16_t)a.w,
                         (bf16_t)b.x, (bf16_t)b.y, (bf16_t)b.z, (bf16_t)b.w };
            *(bf16x8*)&Wl[wr][wkb + 8 * j] = v;
        }
    }

    f32x4 acc[4][2];
    #pragma unroll
    for (int i = 0; i < 4; ++i)
        #pragma unroll
        for (int j = 0; j < 2; ++j) acc[i][j] = 0.f;

    for (int t = 0; t < 6; ++t) {
        const int kb = 32 * t;
        writeX();                                // regs(t) -> LDS (transposed)
        if (t < 5) loadX(t + 1);                 // next loads fly under MFMAs
        __syncthreads();                         // Xl (and Wl at t=0) ready
        bf16x8 af[4], bfr[2];
        #pragma unroll
        for (int mi = 0; mi < 4; ++mi) {
            bf16x4 lo = *(const bf16x4*)&Wl[16 * mi + li][kb + 4 * gi];
            bf16x4 hi = *(const bf16x4*)&Wl[16 * mi + li][kb + 16 + 4 * gi];
            af[mi] = __builtin_shufflevector(lo, hi, 0, 1, 2, 3, 4, 5, 6, 7);
        }
        #pragma unroll
        for (int ni = 0; ni < 2; ++ni) {
            const int n = 32 * w + 16 * ni + li;
            bf16x4 lo = *(const bf16x4*)&Xl[n][4 * gi];
            bf16x4 hi = *(const bf16x4*)&Xl[n][16 + 4 * gi];
            bfr[ni] = __builtin_shufflevector(lo, hi, 0, 1, 2, 3, 4, 5, 6, 7);
        }
        #pragma unroll
        for (int mi = 0; mi < 4; ++mi)
            #pragma unroll
            for (int ni = 0; ni < 2; ++ni)
                acc[mi][ni] = __builtin_amdgcn_mfma_f32_16x16x32_bf16(
                    af[mi], bfr[ni], acc[mi][ni], 0, 0, 0);
        __syncthreads();                         // before next iter's writes
    }
    #pragma unroll
    for (int mi = 0; mi < 4; ++mi)
        #pragma unroll
        for (int ni = 0; ni < 2; ++ni) {
            const int n = n0 + 32 * w + 16 * ni + li;
            #pragma unroll
            for (int r = 0; r < 4; ++r) {
                const int m = m0 + 16 * mi + 4 * gi + r;
                Yb[(long)m * N_PIX + n] = (YT)acc[mi][ni][r];
            }
        }
}

// ---------------- depthwise 3x3 + fused row L2-norm ----------------
// One block = one (channel, image) = one full norm row. For ch<384 (q,k),
// block-reduce sum(z^2) over the 128x128 output and write invn directly.
__global__ __launch_bounds__(256) void dwconv3b(const bf16_t* __restrict__ Yin,
    const float* __restrict__ wdw, bf16_t* __restrict__ Z,
    float* __restrict__ invn)
{
    const int ch = blockIdx.x, sb = blockIdx.y;
    const int tid = threadIdx.x;
    const int x0 = (tid & 15) << 3;          // 16 col-groups x 8
    const int y0 = (tid >> 4) << 3;          // 16 row-strips x 8
    const bf16_t* __restrict__ inp = Yin + (long)(sb * C3 + ch) * N_PIX;
    bf16_t* __restrict__ outp = Z + (long)(sb * C3 + ch) * N_PIX;
    const float* wch = wdw + ch * 9;
    const float w00 = wch[0], w01 = wch[1], w02 = wch[2];
    const float w10 = wch[3], w11 = wch[4], w12 = wch[5];
    const float w20 = wch[6], w21 = wch[7], w22 = wch[8];
    const bool hasL = (x0 > 0), hasR = (x0 < 120);
    float A[10], B[10], Cr[10];   // [0]=x0-1, [1..8]=x0..x0+7, [9]=x0+8
    auto loadrow = [&](int yy, float* r) {
        if (yy < 0 || yy > 127) {
            #pragma unroll
            for (int i = 0; i < 10; ++i) r[i] = 0.f;
            return;
        }
        const bf16_t* p = inp + (yy << 7);
        bf16x8 v = *(const bf16x8*)(p + x0);
        #pragma unroll
        for (int j = 0; j < 8; ++j) r[1 + j] = (float)v[j];
        r[0] = hasL ? (float)p[x0 - 1] : 0.f;
        r[9] = hasR ? (float)p[x0 + 8] : 0.f;
    };
    loadrow(y0 - 1, A);
    loadrow(y0,     B);
    float ss = 0.f;
    #pragma unroll
    for (int r = 0; r < 8; ++r) {
        loadrow(y0 + r + 1, Cr);
        bf16x8 ov;
        #pragma unroll
        for (int i = 0; i < 8; ++i) {
            float s;
            s = fmaf(w00, A[i],  fmaf(w01, A[i + 1],  w02 * A[i + 2]));
            s = fmaf(w10, B[i],  fmaf(w11, B[i + 1],  fmaf(w12, B[i + 2], s)));
            s = fmaf(w20, Cr[i], fmaf(w21, Cr[i + 1], fmaf(w22, Cr[i + 2], s)));
            ov[i] = (bf16_t)s;
            const float vb = (float)ov[i];   // norm of the bf16-rounded value
            ss = fmaf(vb, vb, ss);
        }
        *(bf16x8*)(outp + ((y0 + r) << 7) + x0) = ov;
        #pragma unroll
        for (int i = 0; i < 10; ++i) { A[i] = B[i]; B[i] = Cr[i]; }
    }
    if (ch < 384) {
        #pragma unroll
        for (int off = 32; off > 0; off >>= 1) ss += __shfl_down(ss, off);
        __shared__ float red[4];
        if ((tid & 63) == 0) red[tid >> 6] = ss;
        __syncthreads();
        if (tid == 0) {
            const float t = red[0] + red[1] + red[2] + red[3];
            const int row = (sb >> 2) * 1536 + (sb & 3) * 384 + ch;
            invn[row] = 1.f / fmaxf(sqrtf(t), 1e-12f);
        }
    }
}

// ---------------- MFMA score partials: all 4 combos share one LDS stage ------
// block = (chunk, b*4+h); wave m = combo (ee, dd, ed, de).
__global__ __launch_bounds__(256) void scores_mfma(const bf16_t* __restrict__ Z,
                                                   float* __restrict__ part)
{
    const int c = blockIdx.x;
    const int bh = blockIdx.y;
    const int b = bh >> 2, h = bh & 3;
    __shared__ __align__(16) bf16_t T[4][48][72];   // qe, qd, ke, kd
    const int tid = threadIdx.x;
    const int m = tid >> 6;
    const int gi = (tid >> 4) & 3, li = tid & 15;
    const int qs = (m == 1 || m == 3) ? 1 : 0;
    const int ks = (m == 1 || m == 2) ? 1 : 0;
    f32x4 acc[3][3];
    #pragma unroll
    for (int i = 0; i < 3; ++i)
        #pragma unroll
        for (int j = 0; j < 3; ++j) acc[i][j] = 0.f;

    const int nbase = c * CHUNK;
    for (int k0 = 0; k0 < CHUNK; k0 += 64) {
        __syncthreads();
        for (int l = tid; l < 1536; l += 256) {
            const int t = l / 384;
            const int rem = l - t * 384;
            const int r = rem >> 3, s = rem & 7;
            const int sidx = (t < 2) ? t : (t - 2);
            const int qk = (t < 2) ? 0 : 1;
            const bf16_t* gp = Z + ((long)((sidx * 4 + b) * C3 + qk * 192 + h * 48 + r)) * N_PIX
                                 + nbase + k0 + s * 8;
            *(bf16x8*)&T[t][r][s * 8] = *(const bf16x8*)gp;
        }
        __syncthreads();
        #pragma unroll
        for (int k2 = 0; k2 < 64; k2 += 32) {
            bf16x8 af[3], bfr[3];
            #pragma unroll
            for (int i = 0; i < 3; ++i) {
                bf16x4 lo = *(const bf16x4*)&T[qs][16 * i + li][k2 + 4 * gi];
                bf16x4 hi = *(const bf16x4*)&T[qs][16 * i + li][k2 + 16 + 4 * gi];
                af[i] = __builtin_shufflevector(lo, hi, 0, 1, 2, 3, 4, 5, 6, 7);
            }
            #pragma unroll
            for (int j = 0; j < 3; ++j) {
                bf16x4 lo = *(const bf16x4*)&T[2 + ks][16 * j + li][k2 + 4 * gi];
                bf16x4 hi = *(const bf16x4*)&T[2 + ks][16 * j + li][k2 + 16 + 4 * gi];
                bfr[j] = __builtin_shufflevector(lo, hi, 0, 1, 2, 3, 4, 5, 6, 7);
            }
            #pragma unroll
            for (int i = 0; i < 3; ++i)
                #pragma unroll
                for (int j = 0; j < 3; ++j)
                    acc[i][j] = __builtin_amdgcn_mfma_f32_16x16x32_bf16(
                        af[i], bfr[j], acc[i][j], 0, 0, 0);
        }
    }
    const long base = ((long)(m * 16 + bh) * NCH + c) * 2304;
    #pragma unroll
    for (int i = 0; i < 3; ++i)
        #pragma unroll
        for (int j = 0; j < 3; ++j) {
            const int e = 16 * j + li;
            #pragma unroll
            for (int r = 0; r < 4; ++r) {
                const int d = 16 * i + 4 * gi + r;
                part[base + d * 48 + e] = acc[i][j][r];
            }
        }
}

// ---------------- reduce partials, scale by norms+temperature, softmax -------
__global__ __launch_bounds__(256) void reduce_softmax(const float* __restrict__ part,
    const float* __restrict__ invn, const float* __restrict__ temp,
    float* __restrict__ attn)
{
    const int mbh = blockIdx.x;                 // 64
    const int m = mbh >> 4, b = (mbh >> 2) & 3, h = mbh & 3;
    const int qs = (m == 1 || m == 3) ? 1 : 0;
    const int ks = (m == 1 || m == 2) ? 1 : 0;
    __shared__ float sm[48][48];
    const int tid = threadIdx.x;
    const long pbase = (long)mbh * NCH * 2304;
    const float T = temp[h];
    for (int idx = tid; idx < 2304; idx += 256) {
        float v = 0.f;
        #pragma unroll 8
        for (int c = 0; c < NCH; ++c) v += part[pbase + c * 2304 + idx];
        const int d = idx / 48, e = idx % 48;
        const float iq = invn[(qs * 4 + b) * 384 + h * 48 + d];
        const float ik = invn[(ks * 4 + b) * 384 + 192 + h * 48 + e];
        sm[d][e] = v * iq * ik * T;
    }
    __syncthreads();
    if (tid < 48) {
        float mx = -1e30f;
        #pragma unroll
        for (int e = 0; e < 48; ++e) mx = fmaxf(mx, sm[tid][e]);
        float sum = 0.f;
        #pragma unroll
        for (int e = 0; e < 48; ++e) {
            const float v = __expf(sm[tid][e] - mx);
            sm[tid][e] = v;
            sum += v;
        }
        const float inv = 1.f / sum;
        const long abase = (long)mbh * 2304 + (long)tid * 48;
        #pragma unroll
        for (int e = 0; e < 48; ++e) attn[abase + e] = sm[tid][e] * inv;
    }
}

// ---------------- fold attn into projection: M[m][b][o][h*48+e] --------------
// m==3 (inter_de): einsum '...de,bhen->bhdn' SUMS the ellipsis dims.
__global__ __launch_bounds__(256) void make_M(const float* __restrict__ attn,
                                              WPtrs wp, float* __restrict__ M)
{
    const int h = blockIdx.x & 3;
    const int b = (blockIdx.x >> 2) & 3;
    const int m = blockIdx.x >> 4;              // grid 64
    __shared__ float A[48][48];
    const int tid = threadIdx.x;
    if (m == 3) {
        for (int l = tid; l < 2304; l += 256) {
            float s = 0.f;
            #pragma unroll
            for (int bb = 0; bb < 16; ++bb)
                s += attn[(long)(48 + bb) * 2304 + l];
            A[l / 48][l % 48] = s;
        }
    } else {
        const long ab = (long)(m * 16 + b * 4 + h) * 2304;
        for (int l = tid; l < 2304; l += 256)
            A[l / 48][l % 48] = attn[ab + l];
    }
    __syncthreads();
    const float* W = wp.p[m];
    float* Mo = M + (long)(m * 4 + b) * 192 * 192;
    for (int o = tid >> 4; o < 192; o += 16) {
        const float* wrow = W + (long)o * 192 + h * 48;
        for (int e2 = tid & 15; e2 < 48; e2 += 16) {
            float s = 0.f;
            #pragma unroll
            for (int d = 0; d < 48; ++d) s = fmaf(wrow[d], A[d][e2], s);
            Mo[(long)o * 192 + h * 48 + e2] = s;
        }
    }
}

extern "C" void kernel_launch(void* const* d_in, const int* in_sizes, int n_in,
                              void* d_out, int out_size, void* d_ws, size_t ws_size,
                              hipStream_t stream)
{
    const float* e     = (const float*)d_in[0];
    const float* d     = (const float*)d_in[1];
    const float* temp  = (const float*)d_in[2];
    const float* w_qkv = (const float*)d_in[3];
    const float* w_dw  = (const float*)d_in[4];
    const float* w_p1  = (const float*)d_in[5];
    const float* w_p2  = (const float*)d_in[6];
    const float* w_p3  = (const float*)d_in[7];
    const float* w_p4  = (const float*)d_in[8];
    float* out = (float*)d_out;
    float* ws  = (float*)d_ws;

    // workspace layout (float units)
    bf16_t* zraw = (bf16_t*)ws;                // 75,497,472 bf16 (qkv raw)
    bf16_t* zb   = (bf16_t*)(ws + 37748736L);  // 75,497,472 bf16
    float* attn  = ws + 75497472L;             // 147,456
    float* invn  = ws + 75644928L;             // 3,072
    // part & M reuse the zraw region once it's dead (after dwconv3b)
    float* part  = ws;                         // 4,718,592 f32
    float* Mmat  = ws + 8388608L;              // 589,824 f32

    const long sXin = (long)CC * N_PIX;
    const long sQKV = (long)C3 * N_PIX;

    // 1) pointwise qkv GEMM, bf16 output — ONE launch for e (bt 0..3, X0) and
    //    d (bt 4..7, X1): d-GEMM ramp overlaps e-GEMM drain.
    GArgs gq{};
    for (int bt = 0; bt < 8; ++bt) {
        gq.W[bt] = w_qkv;
        gq.xoff[bt] = (long)(bt & 3) * sXin;
        gq.sel[bt] = bt >> 2;
    }
    gemm_k192<float, bf16_t><<<dim3(128, 9, 8), 256, 0, stream>>>(gq, e, d, zraw, sQKV);
    // 2) depthwise 3x3 (bf16 -> bf16) + fused q/k row norms
    dwconv3b<<<dim3(C3, 8), 256, 0, stream>>>(zraw, w_dw, zb, invn);
    // 3) MFMA score partials, 4 combos fused (part reuses dead zraw region)
    scores_mfma<<<dim3(NCH, 16), 256, 0, stream>>>(zb, part);
    // 4) reduce + scale + softmax
    reduce_softmax<<<dim3(64), 256, 0, stream>>>(part, invn, temp, attn);
    // 5) fold attn into projection matrices
    WPtrs wpj; wpj.p[0] = w_p1; wpj.p[1] = w_p2; wpj.p[2] = w_p3; wpj.p[3] = w_p4;
    make_M<<<dim3(64), 256, 0, stream>>>(attn, wpj, Mmat);
    // 6) fused (proj ∘ attn) @ V directly into d_out (V is bf16)
    GArgs gm{};
    for (int bt = 0; bt < 16; ++bt) {
        const int m = bt >> 2, b = bt & 3;
        const int ks = (m == 1 || m == 2) ? 1 : 0;
        gm.W[bt] = Mmat + (long)bt * 192 * 192;
        gm.xoff[bt] = ((long)((ks * 4 + b) * C3 + 384)) * N_PIX;
        gm.sel[bt] = 0;
    }
    gemm_k192<bf16_t, float><<<dim3(128, 3, 16), 256, 0, stream>>>(gm, zb, zb, out, sXin);
}